// Round 11
// baseline (95.540 us; speedup 1.0000x reference)
//
#include <hip/hip_runtime.h>
#include <hip/hip_bf16.h>
#include <cstdint>
#include <cstddef>

// ---------- types ----------
typedef __bf16 bf16x8 __attribute__((ext_vector_type(8)));
typedef float  f32x4  __attribute__((ext_vector_type(4)));

#define AS1 __attribute__((address_space(1)))
#define AS3 __attribute__((address_space(3)))

static constexpr int B  = 16;
static constexpr int T  = 4096;
static constexpr int D  = 256;
static constexpr int M  = B * T;          // 65536 rows
static constexpr int SEGS = 64;           // segments along T
static constexpr int SEGL = T / SEGS;     // 64 steps per segment

#define RBAR() do { asm volatile("" ::: "memory"); \
                    __builtin_amdgcn_s_barrier();  \
                    asm volatile("" ::: "memory"); } while (0)
#define LGKM0() asm volatile("s_waitcnt lgkmcnt(0)" ::: "memory")
#define VMCNT4() asm volatile("s_waitcnt vmcnt(4)" ::: "memory")
#define VMCNT0() asm volatile("s_waitcnt vmcnt(0)" ::: "memory")

// fast sigmoid: v_exp_f32 + v_rcp_f32 instead of IEEE div (~10 instrs).
__device__ __forceinline__ float sigmoid_fast(float v) {
    return __builtin_amdgcn_rcpf(1.0f + __expf(-v));
}

// ---------- build fragment-major interleaved bf16 weights ----------
// Wp_s element layout: [(ks*32 + fg)*64 + lane] * 8 bf16 elems, where
//   fg = vcol>>4 (0..31), lane = kg*16 + rl, elem ko in [0,8)
//   stored value = W_{s,gate}[rc][ks*32 + kg*8 + ko]
// vcol decomposition: w = fg>>2 (col-wave 0..7), f = fg&3, q = f>>1,
//   gate = f&1, rc = w*32 + 2*rl + q  (lane rl holds 2 ADJACENT real cols)
// One ks-slice of one stage = 16384 elems = 32 KiB, linear in (fg,lane) —
// exactly the shape global_load_lds needs (uniform base + lane*16).
__global__ void cvt_w(const float* __restrict__ W0, const float* __restrict__ W1,
                      const float* __restrict__ W2, const float* __restrict__ W3,
                      __bf16* __restrict__ wp) {
    int i = blockIdx.x * blockDim.x + threadIdx.x;   // 0..32767
    int s    = i >> 14;
    int r    = i & 16383;
    int ks   = r >> 11;          // 0..7
    int fg   = (r >> 6) & 31;    // 0..31
    int lane = r & 63;
    int kg = lane >> 4, rl = lane & 15;
    int w = fg >> 2, f = fg & 3;
    int q = f >> 1, gate = f & 1;
    int rc = w * 32 + 2 * rl + q;
    const float* src = (s == 0) ? (gate ? W1 : W0) : (gate ? W3 : W2);
    const float* p = src + (size_t)rc * 256 + ks * 32 + kg * 8;
    bf16x8 o;
#pragma unroll
    for (int j = 0; j < 8; ++j) o[j] = (__bf16)p[j];
    *reinterpret_cast<bf16x8*>(wp + (size_t)s * 131072 +
                               ((size_t)((ks * 32 + fg) * 64 + lane)) * 8) = o;
}

// ---------- fused two-stage gated-linear + per-segment scan compose ----------
// LDS-STREAMED WEIGHTS (T3/T4): instead of per-wave 2-deep register prefetch
// of B-fragments from L2 (latency-equilibrium stall, the r1..r10 ~63us
// plateau), the whole block streams each 32 KiB ks-slice of Wp into LDS via
// global_load_lds, 3-buffer rotation, counted vmcnt(4), ONE barrier/iter.
// Each slice gets ~2 iterations of flight (> L2 latency); pacing moves to
// per-CU L2 bandwidth. LDS = 32K x/h tile + 3 x 32K wbuf = 128 KiB ->
// 1 block/CU, 8 waves. Flat 16-iter loop = 2 stages x 8 ks; epi0 (h into
// tile, in place) injected at it==8. Biases preloaded to regs in prologue so
// NO vmem op other than the counted gld_lds occurs inside the loop.
__launch_bounds__(512, 2)
__global__ void gln_fused(const float* __restrict__ x,
                          const __bf16* __restrict__ wp,
                          const float* __restrict__ b0, const float* __restrict__ b1,
                          const float* __restrict__ b2, const float* __restrict__ b3,
                          float* __restrict__ out,
                          float2* __restrict__ seg_am) {
    extern __shared__ char smem[];         // 131072 B
    char* tile = smem;                     // [64][256] bf16, chunk-XOR swizzle
    // wbuf i = smem + 32768 + i*32768, i in 0..2

    const int tid  = threadIdx.x;          // 0..511
    const int lane = tid & 63;
    const int wid  = tid >> 6;             // 0..7
    const int rl   = lane & 15;
    const int kg   = lane >> 4;            // 0..3
    const int row0 = blockIdx.x * 64;
    const int rc0  = wid * 32 + 2 * rl;    // even real col of this lane

    // ---- preload ALL biases (keeps the loop free of extra vmem ops) ----
    float2 bb0 = *reinterpret_cast<const float2*>(b0 + rc0);
    float2 bb1 = *reinterpret_cast<const float2*>(b1 + rc0);
    float2 bb2 = *reinterpret_cast<const float2*>(b2 + rc0);
    float2 bb3 = *reinterpret_cast<const float2*>(b3 + rc0);

    // ---- stage x rows [row0, row0+64) into LDS as bf16 ----
    {
        int r  = tid >> 3;         // 0..63
        int c0 = tid & 7;          // base 16B-chunk
        const float* xr = x + (size_t)(row0 + r) * 256;
        float4 xa[4][2];
#pragma unroll
        for (int ci = 0; ci < 4; ++ci) {
            const float4* p = reinterpret_cast<const float4*>(xr + (c0 + ci * 8) * 8);
            xa[ci][0] = p[0];
            xa[ci][1] = p[1];
        }
#pragma unroll
        for (int ci = 0; ci < 4; ++ci) {
            int ck = c0 + ci * 8;  // logical chunk 0..31
            int pc = ck ^ ((r & 7) << 2);
            bf16x8 o = { (__bf16)xa[ci][0].x, (__bf16)xa[ci][0].y,
                         (__bf16)xa[ci][0].z, (__bf16)xa[ci][0].w,
                         (__bf16)xa[ci][1].x, (__bf16)xa[ci][1].y,
                         (__bf16)xa[ci][1].z, (__bf16)xa[ci][1].w };
            *reinterpret_cast<bf16x8*>(&tile[r * 512 + pc * 16]) = o;
        }
    }

    // issue weight slice si (stage = si>>3, ks = si&7) into wbuf[si%3]:
    // 4 x global_load_lds(16B) per thread; dest = wave-uniform base + lane*16.
    auto issueSlice = [&](int si) {
        const char* src = reinterpret_cast<const char*>(wp) + (size_t)si * 32768;
        char* dst = smem + 32768 + (si % 3) * 32768;
#pragma unroll
        for (int ld = 0; ld < 4; ++ld) {
            int ch = ld * 512 + tid;       // 0..2047
            __builtin_amdgcn_global_load_lds(
                (const AS1 void*)(src + (size_t)ch * 16),
                (AS3 void*)(dst + (size_t)ch * 16), 16, 0, 0);
        }
    };
    issueSlice(0);
    issueSlice(1);
    LGKM0();                       // x ds_writes done (published at loop-top bar)

    f32x4 acc[4][4];
#pragma unroll
    for (int m = 0; m < 4; ++m)
#pragma unroll
        for (int f = 0; f < 4; ++f) acc[m][f] = (f32x4){0.f, 0.f, 0.f, 0.f};

    // ---- flat 16-iteration main loop: it = stage*8 + ks ----
#pragma unroll
    for (int it = 0; it < 16; ++it) {
        if (it < 15) { VMCNT4(); } else { VMCNT0(); }   // slice it landed
        RBAR();

        if (it == 8) {
            // epi0: h = (l0+b0)*sigmoid(l1+b1) -> tile in place (x is dead)
            int cb  = rc0 * 2;
            int ck  = cb >> 4;
            int off = cb & 15;
#pragma unroll
            for (int m = 0; m < 4; ++m)
#pragma unroll
                for (int j = 0; j < 4; ++j) {
                    int row = m * 16 + kg * 4 + j;
                    float he = (acc[m][0][j] + bb0.x) * sigmoid_fast(acc[m][1][j] + bb1.x);
                    float ho = (acc[m][2][j] + bb0.y) * sigmoid_fast(acc[m][3][j] + bb1.y);
                    unsigned short ue = __builtin_bit_cast(unsigned short, (__bf16)he);
                    unsigned short uo = __builtin_bit_cast(unsigned short, (__bf16)ho);
                    unsigned int u = ((unsigned int)uo << 16) | (unsigned int)ue;
                    int pc = ck ^ ((row & 7) << 2);
                    *reinterpret_cast<unsigned int*>(&tile[row * 512 + pc * 16 + off]) = u;
                }
            LGKM0(); RBAR();       // h visible block-wide
#pragma unroll
            for (int m = 0; m < 4; ++m)
#pragma unroll
                for (int f = 0; f < 4; ++f) acc[m][f] = (f32x4){0.f, 0.f, 0.f, 0.f};
        }

        const int ks = it & 7;
        const char* wb = smem + 32768 + (it % 3) * 32768;
        bf16x8 bR[4], aR[4];
#pragma unroll
        for (int f = 0; f < 4; ++f)
            bR[f] = *reinterpret_cast<const bf16x8*>(
                wb + ((size_t)((wid * 4 + f) * 64 + lane)) * 16);
#pragma unroll
        for (int m = 0; m < 4; ++m) {
            int row = m * 16 + rl;
            int pc  = (ks * 4 + kg) ^ ((row & 7) << 2);
            aR[m] = *reinterpret_cast<const bf16x8*>(&tile[row * 512 + pc * 16]);
        }
        if (it < 14) issueSlice(it + 2);   // into buffer freed at THIS iter's bar
#pragma unroll
        for (int m = 0; m < 4; ++m)
#pragma unroll
            for (int f = 0; f < 4; ++f)
                acc[m][f] = __builtin_amdgcn_mfma_f32_16x16x32_bf16(
                    aR[m], bR[f], acc[m][f], 0, 0, 0);
    }

    // ---- epi1: gated output -> ov regs ----
    float2 ov[16];
#pragma unroll
    for (int m = 0; m < 4; ++m)
#pragma unroll
        for (int j = 0; j < 4; ++j) {
            float he = (acc[m][0][j] + bb2.x) * sigmoid_fast(acc[m][1][j] + bb3.x);
            float ho = (acc[m][2][j] + bb2.y) * sigmoid_fast(acc[m][3][j] + bb3.y);
            float2 o; o.x = he; o.y = ho;
            ov[m * 4 + j] = o;
        }
    RBAR();                        // all stage-1 h reads done; tile reusable

    // ---- row-split ftile + fused scan_seg compose (state in regs) ----
    float* ftile = reinterpret_cast<float*>(tile);   // [32][256] f32 = 32 KiB
#pragma unroll
    for (int m = 0; m < 2; ++m)
#pragma unroll
        for (int j = 0; j < 4; ++j) {
            int row = m * 16 + kg * 4 + j;
            int col = rc0 ^ ((row & 7) << 2);
            *reinterpret_cast<float2*>(&ftile[row * 256 + col]) = ov[m * 4 + j];
        }
    LGKM0(); RBAR();

    const int batch = row0 >> 12;          // row0 / T
    const int t0    = row0 & 4095;
    const int seg   = t0 >> 6;
    float A = 0.f, Mx = -1e30f;
    int cc = 0;
    if (tid < 256) {
        cc = (tid + t0) & 255;
#pragma unroll 8
        for (int i = 0; i < 32; ++i) {
            int col = ((cc + i) & 255) ^ ((i & 7) << 2);
            float v = ftile[i * 256 + col];
            A += v;
            Mx = fmaxf(Mx + v, 0.f);
        }
    }
    RBAR();                        // part-1 reads consumed before overwrite
#pragma unroll
    for (int m = 2; m < 4; ++m)
#pragma unroll
        for (int j = 0; j < 4; ++j) {
            int row = m * 16 + kg * 4 + j;
            int pr  = row & 31;
            int col = rc0 ^ ((pr & 7) << 2);
            *reinterpret_cast<float2*>(&ftile[pr * 256 + col]) = ov[m * 4 + j];
        }

    // global stores: not drained by the raw barrier below; overlap compose
#pragma unroll
    for (int m = 0; m < 4; ++m)
#pragma unroll
        for (int j = 0; j < 4; ++j) {
            int row = m * 16 + kg * 4 + j;
            *reinterpret_cast<float2*>(out + (size_t)(row0 + row) * 256 + rc0) =
                ov[m * 4 + j];
        }
    LGKM0(); RBAR();

    if (tid < 256) {
#pragma unroll 8
        for (int i = 32; i < 64; ++i) {
            int pr  = i - 32;
            int col = ((cc + i) & 255) ^ ((pr & 7) << 2);
            float v = ftile[pr * 256 + col];
            A += v;
            Mx = fmaxf(Mx + v, 0.f);
        }
        float2 o; o.x = A; o.y = Mx;
        seg_am[(size_t)(batch * SEGS + seg) * 256 + tid] = o;
    }
    // stores drain at wave retirement
}

// ---------- scan apply with integrated boundary lookback ----------
// Block = one (batch, seg) x 256 cols. Redundantly composes seg_am[0..seg)
// (<=63 serial fmax steps, L2/L3-resident).
__global__ void scan_apply(float* __restrict__ bio,
                           const float2* __restrict__ seg_am,
                           const float* __restrict__ hidden,
                           float* __restrict__ last) {
    int tid   = blockIdx.x * blockDim.x + threadIdx.x;
    int c     = tid & 255;
    int rest  = tid >> 8;
    int batch = rest & 15;
    int seg   = rest >> 4;
    float s = hidden[batch * 256 + ((c + 255) & 255)];
    const float2* am = seg_am + ((size_t)batch * SEGS) * 256 + c;
    for (int k = 0; k < seg; ++k) {
        float2 a = am[(size_t)k * 256];
        s = fmaxf(s + a.x, a.y);
    }
    float* base = bio + (size_t)batch * T * D;
    int t0 = seg * SEGL;
#pragma unroll 8
    for (int i = 0; i < SEGL; ++i) {
        int t = t0 + i;
        size_t idx = (size_t)t * 256 + ((c + t) & 255);
        float v = base[idx];
        s = fmaxf(s + v, 0.f);
        base[idx] = s;
    }
    if (seg == SEGS - 1) last[batch * 256 + ((c + 255) & 255)] = s;
}

// ---------- launch ----------
extern "C" void kernel_launch(void* const* d_in, const int* in_sizes, int n_in,
                              void* d_out, int out_size, void* d_ws, size_t ws_size,
                              hipStream_t stream) {
    const float* x      = (const float*)d_in[0];
    const float* hidden = (const float*)d_in[1];
    const float* W0 = (const float*)d_in[2];
    const float* b0 = (const float*)d_in[3];
    const float* W1 = (const float*)d_in[4];
    const float* b1 = (const float*)d_in[5];
    const float* W2 = (const float*)d_in[6];
    const float* b2 = (const float*)d_in[7];
    const float* W3 = (const float*)d_in[8];
    const float* b3 = (const float*)d_in[9];

    float* out  = (float*)d_out;
    float* last = out + (size_t)M * D;

    char* ws = (char*)d_ws;
    __bf16* wpb    = (__bf16*)ws;                 // 524,288 B (Wp0, Wp1)
    float2* seg_am = (float2*)(ws + 524288);      // 2,097,152 B

    static bool attr_done = false;
    if (!attr_done) {
        hipFuncSetAttribute(reinterpret_cast<const void*>(&gln_fused),
                            hipFuncAttributeMaxDynamicSharedMemorySize, 131072);
        attr_done = true;
    }

    cvt_w<<<128, 256, 0, stream>>>(W0, W1, W2, W3, wpb);
    gln_fused<<<M / 64, 512, 131072, stream>>>(x, wpb, b0, b1, b2, b3, out, seg_am);
    scan_apply<<<(B * D * SEGS) / 256, 256, 0, stream>>>(out, seg_am, hidden, last);
}

// Round 12
// 92.284 us; speedup vs baseline: 1.0353x; 1.0353x over previous
//
#include <hip/hip_runtime.h>
#include <hip/hip_bf16.h>
#include <cstdint>
#include <cstddef>

// ---------- types ----------
typedef __bf16 bf16x8 __attribute__((ext_vector_type(8)));
typedef float  f32x4  __attribute__((ext_vector_type(4)));

static constexpr int B  = 16;
static constexpr int T  = 4096;
static constexpr int D  = 256;
static constexpr int M  = B * T;          // 65536 rows
static constexpr int SEGS = 64;           // segments along T
static constexpr int SEGL = T / SEGS;     // 64 steps per segment

// raw barrier (no vmcnt(0) drain) + compiler fences; LGKM0 fences LDS
// producer->consumer edges. Global prefetches/stores stay in flight across
// barriers; consumers are guarded by compiler-inserted vmcnt data-dep waits.
#define RBAR() do { asm volatile("" ::: "memory"); \
                    __builtin_amdgcn_s_barrier();  \
                    asm volatile("" ::: "memory"); } while (0)
#define LGKM0() asm volatile("s_waitcnt lgkmcnt(0)" ::: "memory")

static constexpr float NLOG2E = -1.4426950408889634f;

// fast sigmoid with pre-scaled bias: rcp(1 + exp2(acc*-log2e + bbn)),
// bbn = -log2e * bias. One FMA + v_exp + v_rcp.
__device__ __forceinline__ float sigmoid_e2(float a, float bbn) {
    return __builtin_amdgcn_rcpf(1.0f + exp2f(fmaf(a, NLOG2E, bbn)));
}

// ---------- build fragment-major interleaved bf16 weights ----------
// Wp_s element layout: [(ks*32 + fg)*64 + lane] * 8 bf16 elems, where
//   fg = vcol>>4 (0..31), lane = kg*16 + rl, elem ko in [0,8)
//   stored value = W_{s,gate}[rc][ks*32 + kg*8 + ko]
// vcol decomposition: w = fg>>2 (col-wave 0..7), f = fg&3, q = f>>1,
//   gate = f&1, rc = w*32 + 2*rl + q  (lane rl holds 2 ADJACENT real cols)
__global__ void cvt_w(const float* __restrict__ W0, const float* __restrict__ W1,
                      const float* __restrict__ W2, const float* __restrict__ W3,
                      __bf16* __restrict__ wp) {
    int i = blockIdx.x * blockDim.x + threadIdx.x;   // 0..32767
    int s    = i >> 14;
    int r    = i & 16383;
    int ks   = r >> 11;          // 0..7
    int fg   = (r >> 6) & 31;    // 0..31
    int lane = r & 63;
    int kg = lane >> 4, rl = lane & 15;
    int w = fg >> 2, f = fg & 3;
    int q = f >> 1, gate = f & 1;
    int rc = w * 32 + 2 * rl + q;
    const float* src = (s == 0) ? (gate ? W1 : W0) : (gate ? W3 : W2);
    const float* p = src + (size_t)rc * 256 + ks * 32 + kg * 8;
    bf16x8 o;
#pragma unroll
    for (int j = 0; j < 8; ++j) o[j] = (__bf16)p[j];
    *reinterpret_cast<bf16x8*>(wp + (size_t)s * 131072 +
                               ((size_t)((ks * 32 + fg) * 64 + lane)) * 8) = o;
}

// ---------- fused two-stage gated-linear + per-segment scan compose ----------
// r10 structure (single 64-row tile, 512 thr / 8 waves, 32 KiB LDS, raw
// barriers, 2 blocks/CU) with the B-prefetch pipeline DEEPENED to 2-iteration
// coverage at the same register cost: frag f of slice ks+2 is issued right
// after the 4 MFMAs that consume frag f of slice ks (same 2 buffers; the
// old schedule loaded ks+1 at top of iter ks = 1-iteration coverage < L2
// latency -> per-iteration vmcnt stall, the ~63us plateau's suspect).
__launch_bounds__(512, 4)
__global__ void gln_fused(const float* __restrict__ x,
                          const __bf16* __restrict__ wp,
                          const float* __restrict__ b0, const float* __restrict__ b1,
                          const float* __restrict__ b2, const float* __restrict__ b3,
                          float* __restrict__ out,
                          float2* __restrict__ seg_am) {
    __shared__ char tile[32768];           // [64][256] bf16, chunk-XOR swizzle

    const int tid  = threadIdx.x;          // 0..511
    const int lane = tid & 63;
    const int wid  = tid >> 6;             // 0..7
    const int rl   = lane & 15;
    const int kg   = lane >> 4;            // 0..3
    const int row0 = blockIdx.x * 64;

    const __bf16* wv0 = wp + ((size_t)(wid * 4) * 64 + lane) * 8;
    const __bf16* wv1 = wv0 + 131072;

    bf16x8 bbuf[2][4];
    auto loadB = [&](int p, const __bf16* wvb, int ks) {
#pragma unroll
        for (int f = 0; f < 4; ++f)
            bbuf[p][f] = *reinterpret_cast<const bf16x8*>(wvb + ks * 16384 + f * 512);
    };

    // ---- stage x rows [row0, row0+64) into LDS as bf16 ----
    {
        int r  = tid >> 3;         // 0..63
        int c0 = tid & 7;          // base 16B-chunk
        const float* xr = x + (size_t)(row0 + r) * 256;
        float4 xa[4][2];
#pragma unroll
        for (int ci = 0; ci < 4; ++ci) {
            const float4* p = reinterpret_cast<const float4*>(xr + (c0 + ci * 8) * 8);
            xa[ci][0] = p[0];
            xa[ci][1] = p[1];
        }
#pragma unroll
        for (int ci = 0; ci < 4; ++ci) {
            int ck = c0 + ci * 8;  // logical chunk 0..31
            int pc = ck ^ ((r & 7) << 2);
            bf16x8 o = { (__bf16)xa[ci][0].x, (__bf16)xa[ci][0].y,
                         (__bf16)xa[ci][0].z, (__bf16)xa[ci][0].w,
                         (__bf16)xa[ci][1].x, (__bf16)xa[ci][1].y,
                         (__bf16)xa[ci][1].z, (__bf16)xa[ci][1].w };
            *reinterpret_cast<bf16x8*>(&tile[r * 512 + pc * 16]) = o;
        }
    }
    loadB(0, wv0, 0);              // ks0 + ks1 in flight across raw barrier
    loadB(1, wv0, 1);
    LGKM0(); RBAR();

    f32x4 acc[4][4];

    // one GEMM stage. Entry contract: bbuf[0]=ks0, bbuf[1]=ks1 of this stage.
    // Iter ks: consume bbuf[ks&1]; after the 4 MFMAs reading frag f, reload
    // that frag slot with slice ks+2 (2-iteration flight > L2 latency).
    auto run_stage = [&](const __bf16* wvb) {
#pragma unroll
        for (int m = 0; m < 4; ++m)
#pragma unroll
            for (int f = 0; f < 4; ++f) acc[m][f] = (f32x4){0.f, 0.f, 0.f, 0.f};
#pragma unroll
        for (int ks = 0; ks < 8; ++ks) {
            bf16x8 aR[4];
#pragma unroll
            for (int m = 0; m < 4; ++m) {
                int row = m * 16 + rl;
                int pc  = (ks * 4 + kg) ^ ((row & 7) << 2);
                aR[m] = *reinterpret_cast<const bf16x8*>(&tile[row * 512 + pc * 16]);
            }
#pragma unroll
            for (int f = 0; f < 4; ++f) {
#pragma unroll
                for (int m = 0; m < 4; ++m)
                    acc[m][f] = __builtin_amdgcn_mfma_f32_16x16x32_bf16(
                        aR[m], bbuf[ks & 1][f], acc[m][f], 0, 0, 0);
                if (ks < 6)        // refill just-freed slot with slice ks+2
                    bbuf[ks & 1][f] = *reinterpret_cast<const bf16x8*>(
                        wvb + (ks + 2) * 16384 + f * 512);
            }
        }
    };

    const int rc0 = wid * 32 + 2 * rl;     // even real col of this lane

    // ---- stage 0: h = (x@W0^T+b0) * sigmoid(x@W1^T+b1) ----
    run_stage(wv0);
    loadB(0, wv1, 0);              // stage-1 ks0/ks1; covered by epi0+barriers
    loadB(1, wv1, 1);
    RBAR();                        // x reads consumed (data-dep); overwrite ok
    {
        float2 bb0 = *reinterpret_cast<const float2*>(b0 + rc0);
        float2 bb1 = *reinterpret_cast<const float2*>(b1 + rc0);
        float bn1x = NLOG2E * bb1.x, bn1y = NLOG2E * bb1.y;
        int cb  = rc0 * 2;                 // byte col (4-aligned)
        int ck  = cb >> 4;                 // logical chunk
        int off = cb & 15;
#pragma unroll
        for (int m = 0; m < 4; ++m)
#pragma unroll
            for (int j = 0; j < 4; ++j) {
                int row = m * 16 + kg * 4 + j;
                float he = (acc[m][0][j] + bb0.x) * sigmoid_e2(acc[m][1][j], bn1x);
                float ho = (acc[m][2][j] + bb0.y) * sigmoid_e2(acc[m][3][j], bn1y);
                unsigned short ue = __builtin_bit_cast(unsigned short, (__bf16)he);
                unsigned short uo = __builtin_bit_cast(unsigned short, (__bf16)ho);
                unsigned int u = ((unsigned int)uo << 16) | (unsigned int)ue;
                int pc = ck ^ ((row & 7) << 2);
                *reinterpret_cast<unsigned int*>(&tile[row * 512 + pc * 16 + off]) = u;
            }
    }
    LGKM0(); RBAR();

    // ---- stage 1: out = (h@W2^T+b2) * sigmoid(h@W3^T+b3) ----
    run_stage(wv1);

    // epilogue: gated values -> regs only
    float2 ov[16];
    {
        float2 bb2 = *reinterpret_cast<const float2*>(b2 + rc0);
        float2 bb3 = *reinterpret_cast<const float2*>(b3 + rc0);
        float bn3x = NLOG2E * bb3.x, bn3y = NLOG2E * bb3.y;
#pragma unroll
        for (int m = 0; m < 4; ++m)
#pragma unroll
            for (int j = 0; j < 4; ++j) {
                float he = (acc[m][0][j] + bb2.x) * sigmoid_e2(acc[m][1][j], bn3x);
                float ho = (acc[m][2][j] + bb2.y) * sigmoid_e2(acc[m][3][j], bn3y);
                float2 o; o.x = he; o.y = ho;
                ov[m * 4 + j] = o;
            }
    }
    RBAR();                        // h reads consumed; tile reusable

    // ---- row-split ftile + fused scan_seg compose (state in regs) ----
    float* ftile = reinterpret_cast<float*>(tile);   // [32][256] f32 = 32 KiB
#pragma unroll
    for (int m = 0; m < 2; ++m)
#pragma unroll
        for (int j = 0; j < 4; ++j) {
            int row = m * 16 + kg * 4 + j;
            int col = rc0 ^ ((row & 7) << 2);
            *reinterpret_cast<float2*>(&ftile[row * 256 + col]) = ov[m * 4 + j];
        }
    LGKM0(); RBAR();

    const int batch = row0 >> 12;          // row0 / T
    const int t0    = row0 & 4095;
    const int seg   = t0 >> 6;
    float A = 0.f, Mx = -1e30f;
    int cc = 0;
    if (tid < 256) {
        cc = (tid + t0) & 255;
#pragma unroll 8
        for (int i = 0; i < 32; ++i) {
            int col = ((cc + i) & 255) ^ ((i & 7) << 2);
            float v = ftile[i * 256 + col];
            A += v;
            Mx = fmaxf(Mx + v, 0.f);
        }
    }
    RBAR();                        // part-1 reads consumed before overwrite
#pragma unroll
    for (int m = 2; m < 4; ++m)
#pragma unroll
        for (int j = 0; j < 4; ++j) {
            int row = m * 16 + kg * 4 + j;
            int pr  = row & 31;
            int col = rc0 ^ ((pr & 7) << 2);
            *reinterpret_cast<float2*>(&ftile[pr * 256 + col]) = ov[m * 4 + j];
        }

    // global stores: not drained by the raw barrier below; overlap compose
#pragma unroll
    for (int m = 0; m < 4; ++m)
#pragma unroll
        for (int j = 0; j < 4; ++j) {
            int row = m * 16 + kg * 4 + j;
            *reinterpret_cast<float2*>(out + (size_t)(row0 + row) * 256 + rc0) =
                ov[m * 4 + j];
        }
    LGKM0(); RBAR();

    if (tid < 256) {
#pragma unroll 8
        for (int i = 32; i < 64; ++i) {
            int pr  = i - 32;
            int col = ((cc + i) & 255) ^ ((pr & 7) << 2);
            float v = ftile[pr * 256 + col];
            A += v;
            Mx = fmaxf(Mx + v, 0.f);
        }
        float2 o; o.x = A; o.y = Mx;
        seg_am[(size_t)(batch * SEGS + seg) * 256 + tid] = o;
    }
    // stores drain at wave retirement
}

// ---------- scan apply with integrated boundary lookback ----------
// Block = one (batch, seg) x 256 cols. Redundantly composes seg_am[0..seg)
// (<=63 serial fmax steps, L2/L3-resident).
__global__ void scan_apply(float* __restrict__ bio,
                           const float2* __restrict__ seg_am,
                           const float* __restrict__ hidden,
                           float* __restrict__ last) {
    int tid   = blockIdx.x * blockDim.x + threadIdx.x;
    int c     = tid & 255;
    int rest  = tid >> 8;
    int batch = rest & 15;
    int seg   = rest >> 4;
    float s = hidden[batch * 256 + ((c + 255) & 255)];
    const float2* am = seg_am + ((size_t)batch * SEGS) * 256 + c;
    for (int k = 0; k < seg; ++k) {
        float2 a = am[(size_t)k * 256];
        s = fmaxf(s + a.x, a.y);
    }
    float* base = bio + (size_t)batch * T * D;
    int t0 = seg * SEGL;
#pragma unroll 8
    for (int i = 0; i < SEGL; ++i) {
        int t = t0 + i;
        size_t idx = (size_t)t * 256 + ((c + t) & 255);
        float v = base[idx];
        s = fmaxf(s + v, 0.f);
        base[idx] = s;
    }
    if (seg == SEGS - 1) last[batch * 256 + ((c + 255) & 255)] = s;
}

// ---------- launch ----------
extern "C" void kernel_launch(void* const* d_in, const int* in_sizes, int n_in,
                              void* d_out, int out_size, void* d_ws, size_t ws_size,
                              hipStream_t stream) {
    const float* x      = (const float*)d_in[0];
    const float* hidden = (const float*)d_in[1];
    const float* W0 = (const float*)d_in[2];
    const float* b0 = (const float*)d_in[3];
    const float* W1 = (const float*)d_in[4];
    const float* b1 = (const float*)d_in[5];
    const float* W2 = (const float*)d_in[6];
    const float* b2 = (const float*)d_in[7];
    const float* W3 = (const float*)d_in[8];
    const float* b3 = (const float*)d_in[9];

    float* out  = (float*)d_out;
    float* last = out + (size_t)M * D;

    char* ws = (char*)d_ws;
    __bf16* wpb    = (__bf16*)ws;                 // 524,288 B (Wp0, Wp1)
    float2* seg_am = (float2*)(ws + 524288);      // 2,097,152 B

    cvt_w<<<128, 256, 0, stream>>>(W0, W1, W2, W3, wpb);
    gln_fused<<<M / 64, 512, 0, stream>>>(x, wpb, b0, b1, b2, b3, out, seg_am);
    scan_apply<<<(B * D * SEGS) / 256, 256, 0, stream>>>(out, seg_am, hidden, last);
}

// Round 13
// 85.410 us; speedup vs baseline: 1.1186x; 1.0805x over previous
//
#include <hip/hip_runtime.h>
#include <hip/hip_bf16.h>
#include <cstdint>
#include <cstddef>

// ---------- types ----------
typedef __bf16 bf16x8 __attribute__((ext_vector_type(8)));
typedef float  f32x4  __attribute__((ext_vector_type(4)));

static constexpr int B  = 16;
static constexpr int T  = 4096;
static constexpr int D  = 256;
static constexpr int M  = B * T;          // 65536 rows
static constexpr int SEGS = 64;           // segments along T
static constexpr int SEGL = T / SEGS;     // 64 steps per segment

// raw barrier (no vmcnt(0) drain) + compiler fences; LGKM0 fences LDS
// producer->consumer edges. Global prefetches/stores stay in flight across
// barriers; consumers are guarded by compiler-inserted vmcnt data-dep waits.
#define RBAR() do { asm volatile("" ::: "memory"); \
                    __builtin_amdgcn_s_barrier();  \
                    asm volatile("" ::: "memory"); } while (0)
#define LGKM0() asm volatile("s_waitcnt lgkmcnt(0)" ::: "memory")

static constexpr float NLOG2E = -1.4426950408889634f;

// fast sigmoid with pre-scaled bias: rcp(1 + exp2(acc*-log2e + bbn)),
// bbn = -log2e * bias. One FMA + v_exp_f32 + v_rcp_f32.
__device__ __forceinline__ float sigmoid_e2(float a, float bbn) {
    return __builtin_amdgcn_rcpf(1.0f + exp2f(fmaf(a, NLOG2E, bbn)));
}

// ---------- build fragment-major interleaved bf16 weights ----------
// Wp_s element layout: [(ks*32 + fg)*64 + lane] * 8 bf16 elems, where
//   fg = vcol>>4 (0..31), lane = kg*16 + rl, elem ko in [0,8)
//   stored value = W_{s,gate}[rc][ks*32 + kg*8 + ko]
// vcol decomposition: w = fg>>2 (col-wave 0..7), f = fg&3, q = f>>1,
//   gate = f&1, rc = w*32 + 2*rl + q  (lane rl holds 2 ADJACENT real cols)
__global__ void cvt_w(const float* __restrict__ W0, const float* __restrict__ W1,
                      const float* __restrict__ W2, const float* __restrict__ W3,
                      __bf16* __restrict__ wp) {
    int i = blockIdx.x * blockDim.x + threadIdx.x;   // 0..32767
    int s    = i >> 14;
    int r    = i & 16383;
    int ks   = r >> 11;          // 0..7
    int fg   = (r >> 6) & 31;    // 0..31
    int lane = r & 63;
    int kg = lane >> 4, rl = lane & 15;
    int w = fg >> 2, f = fg & 3;
    int q = f >> 1, gate = f & 1;
    int rc = w * 32 + 2 * rl + q;
    const float* src = (s == 0) ? (gate ? W1 : W0) : (gate ? W3 : W2);
    const float* p = src + (size_t)rc * 256 + ks * 32 + kg * 8;
    bf16x8 o;
#pragma unroll
    for (int j = 0; j < 8; ++j) o[j] = (__bf16)p[j];
    *reinterpret_cast<bf16x8*>(wp + (size_t)s * 131072 +
                               ((size_t)((ks * 32 + fg) * 64 + lane)) * 8) = o;
}

// ---------- fused two-stage gated-linear + per-segment scan compose ----------
// EXACT r10 structure (verified best: single 64-row tile, 512 thr / 8 waves,
// 32 KiB LDS, raw barriers, top-of-loop 2-deep B prefetch, 2 blocks/CU).
// Only delta vs r10: sigmoid_e2 (bias folded into one FMA before v_exp).
// Falsified this session: occupancy-bound (r5), A-read bank conflicts (r6),
// barrier vmcnt-drain (r10), LDS weight streaming (r11), deeper B-prefetch
// (r12). Confirmed: epilogue VALU on critical path (r8), scan fusion ~free
// when ordered ftile->bar->stores->compose (r7).
__launch_bounds__(512, 4)
__global__ void gln_fused(const float* __restrict__ x,
                          const __bf16* __restrict__ wp,
                          const float* __restrict__ b0, const float* __restrict__ b1,
                          const float* __restrict__ b2, const float* __restrict__ b3,
                          float* __restrict__ out,
                          float2* __restrict__ seg_am) {
    __shared__ char tile[32768];           // [64][256] bf16, chunk-XOR swizzle

    const int tid  = threadIdx.x;          // 0..511
    const int lane = tid & 63;
    const int wid  = tid >> 6;             // 0..7
    const int rl   = lane & 15;
    const int kg   = lane >> 4;            // 0..3
    const int row0 = blockIdx.x * 64;

    const __bf16* wv0 = wp + ((size_t)(wid * 4) * 64 + lane) * 8;
    const __bf16* wv1 = wv0 + 131072;

    bf16x8 bbuf[2][4];
    auto loadB = [&](int p, const __bf16* wvb, int ks) {
#pragma unroll
        for (int f = 0; f < 4; ++f)
            bbuf[p][f] = *reinterpret_cast<const bf16x8*>(wvb + ks * 16384 + f * 512);
    };

    // ---- stage x rows [row0, row0+64) into LDS as bf16 ----
    {
        int r  = tid >> 3;         // 0..63
        int c0 = tid & 7;          // base 16B-chunk
        const float* xr = x + (size_t)(row0 + r) * 256;
        float4 xa[4][2];
#pragma unroll
        for (int ci = 0; ci < 4; ++ci) {
            const float4* p = reinterpret_cast<const float4*>(xr + (c0 + ci * 8) * 8);
            xa[ci][0] = p[0];
            xa[ci][1] = p[1];
        }
#pragma unroll
        for (int ci = 0; ci < 4; ++ci) {
            int ck = c0 + ci * 8;  // logical chunk 0..31
            int pc = ck ^ ((r & 7) << 2);
            bf16x8 o = { (__bf16)xa[ci][0].x, (__bf16)xa[ci][0].y,
                         (__bf16)xa[ci][0].z, (__bf16)xa[ci][0].w,
                         (__bf16)xa[ci][1].x, (__bf16)xa[ci][1].y,
                         (__bf16)xa[ci][1].z, (__bf16)xa[ci][1].w };
            *reinterpret_cast<bf16x8*>(&tile[r * 512 + pc * 16]) = o;
        }
    }
    loadB(0, wv0, 0);              // stays in flight across raw barrier
    LGKM0(); RBAR();

    f32x4 acc[4][4];

    // one GEMM stage: A from LDS (64 rows, K=256), B 2-deep pipelined from L2.
    auto run_stage = [&](const __bf16* wvb) {
#pragma unroll
        for (int m = 0; m < 4; ++m)
#pragma unroll
            for (int f = 0; f < 4; ++f) acc[m][f] = (f32x4){0.f, 0.f, 0.f, 0.f};
#pragma unroll
        for (int ks = 0; ks < 8; ++ks) {
            if (ks < 7) loadB((ks + 1) & 1, wvb, ks + 1);   // prefetch next ks
            bf16x8 aR[4];
#pragma unroll
            for (int m = 0; m < 4; ++m) {
                int row = m * 16 + rl;
                int pc  = (ks * 4 + kg) ^ ((row & 7) << 2);
                aR[m] = *reinterpret_cast<const bf16x8*>(&tile[row * 512 + pc * 16]);
            }
#pragma unroll
            for (int m = 0; m < 4; ++m)
#pragma unroll
                for (int f = 0; f < 4; ++f)
                    acc[m][f] = __builtin_amdgcn_mfma_f32_16x16x32_bf16(
                        aR[m], bbuf[ks & 1][f], acc[m][f], 0, 0, 0);
        }
    };

    const int rc0 = wid * 32 + 2 * rl;     // even real col of this lane

    // ---- stage 0: h = (x@W0^T+b0) * sigmoid(x@W1^T+b1) ----
    run_stage(wv0);
    loadB(0, wv1, 0);              // stage-1 ks0 prefetch (survives barriers)
    RBAR();                        // x reads consumed (data-dep); overwrite ok
    {
        float2 bb0 = *reinterpret_cast<const float2*>(b0 + rc0);
        float2 bb1 = *reinterpret_cast<const float2*>(b1 + rc0);
        float bn1x = NLOG2E * bb1.x, bn1y = NLOG2E * bb1.y;
        int cb  = rc0 * 2;                 // byte col (4-aligned)
        int ck  = cb >> 4;                 // logical chunk
        int off = cb & 15;
#pragma unroll
        for (int m = 0; m < 4; ++m)
#pragma unroll
            for (int j = 0; j < 4; ++j) {
                int row = m * 16 + kg * 4 + j;
                float he = (acc[m][0][j] + bb0.x) * sigmoid_e2(acc[m][1][j], bn1x);
                float ho = (acc[m][2][j] + bb0.y) * sigmoid_e2(acc[m][3][j], bn1y);
                unsigned short ue = __builtin_bit_cast(unsigned short, (__bf16)he);
                unsigned short uo = __builtin_bit_cast(unsigned short, (__bf16)ho);
                unsigned int u = ((unsigned int)uo << 16) | (unsigned int)ue;
                int pc = ck ^ ((row & 7) << 2);
                *reinterpret_cast<unsigned int*>(&tile[row * 512 + pc * 16 + off]) = u;
            }
    }
    LGKM0(); RBAR();

    // ---- stage 1: out = (h@W2^T+b2) * sigmoid(h@W3^T+b3) ----
    run_stage(wv1);

    // epilogue: gated values -> regs only
    float2 ov[16];
    {
        float2 bb2 = *reinterpret_cast<const float2*>(b2 + rc0);
        float2 bb3 = *reinterpret_cast<const float2*>(b3 + rc0);
        float bn3x = NLOG2E * bb3.x, bn3y = NLOG2E * bb3.y;
#pragma unroll
        for (int m = 0; m < 4; ++m)
#pragma unroll
            for (int j = 0; j < 4; ++j) {
                float he = (acc[m][0][j] + bb2.x) * sigmoid_e2(acc[m][1][j], bn3x);
                float ho = (acc[m][2][j] + bb2.y) * sigmoid_e2(acc[m][3][j], bn3y);
                float2 o; o.x = he; o.y = ho;
                ov[m * 4 + j] = o;
            }
    }
    RBAR();                        // h reads consumed; tile reusable

    // ---- row-split ftile + fused scan_seg compose (state in regs) ----
    float* ftile = reinterpret_cast<float*>(tile);   // [32][256] f32 = 32 KiB
#pragma unroll
    for (int m = 0; m < 2; ++m)
#pragma unroll
        for (int j = 0; j < 4; ++j) {
            int row = m * 16 + kg * 4 + j;
            int col = rc0 ^ ((row & 7) << 2);
            *reinterpret_cast<float2*>(&ftile[row * 256 + col]) = ov[m * 4 + j];
        }
    LGKM0(); RBAR();

    const int batch = row0 >> 12;          // row0 / T
    const int t0    = row0 & 4095;
    const int seg   = t0 >> 6;
    float A = 0.f, Mx = -1e30f;
    int cc = 0;
    if (tid < 256) {
        cc = (tid + t0) & 255;
#pragma unroll 8
        for (int i = 0; i < 32; ++i) {
            int col = ((cc + i) & 255) ^ ((i & 7) << 2);
            float v = ftile[i * 256 + col];
            A += v;
            Mx = fmaxf(Mx + v, 0.f);
        }
    }
    RBAR();                        // part-1 reads consumed before overwrite
#pragma unroll
    for (int m = 2; m < 4; ++m)
#pragma unroll
        for (int j = 0; j < 4; ++j) {
            int row = m * 16 + kg * 4 + j;
            int pr  = row & 31;
            int col = rc0 ^ ((pr & 7) << 2);
            *reinterpret_cast<float2*>(&ftile[pr * 256 + col]) = ov[m * 4 + j];
        }

    // global stores: not drained by the raw barrier below; overlap compose
#pragma unroll
    for (int m = 0; m < 4; ++m)
#pragma unroll
        for (int j = 0; j < 4; ++j) {
            int row = m * 16 + kg * 4 + j;
            *reinterpret_cast<float2*>(out + (size_t)(row0 + row) * 256 + rc0) =
                ov[m * 4 + j];
        }
    LGKM0(); RBAR();

    if (tid < 256) {
#pragma unroll 8
        for (int i = 32; i < 64; ++i) {
            int pr  = i - 32;
            int col = ((cc + i) & 255) ^ ((pr & 7) << 2);
            float v = ftile[pr * 256 + col];
            A += v;
            Mx = fmaxf(Mx + v, 0.f);
        }
        float2 o; o.x = A; o.y = Mx;
        seg_am[(size_t)(batch * SEGS + seg) * 256 + tid] = o;
    }
    // stores drain at wave retirement
}

// ---------- scan apply with integrated boundary lookback ----------
// Block = one (batch, seg) x 256 cols. Redundantly composes seg_am[0..seg)
// (<=63 serial fmax steps, L2/L3-resident).
__global__ void scan_apply(float* __restrict__ bio,
                           const float2* __restrict__ seg_am,
                           const float* __restrict__ hidden,
                           float* __restrict__ last) {
    int tid   = blockIdx.x * blockDim.x + threadIdx.x;
    int c     = tid & 255;
    int rest  = tid >> 8;
    int batch = rest & 15;
    int seg   = rest >> 4;
    float s = hidden[batch * 256 + ((c + 255) & 255)];
    const float2* am = seg_am + ((size_t)batch * SEGS) * 256 + c;
    for (int k = 0; k < seg; ++k) {
        float2 a = am[(size_t)k * 256];
        s = fmaxf(s + a.x, a.y);
    }
    float* base = bio + (size_t)batch * T * D;
    int t0 = seg * SEGL;
#pragma unroll 8
    for (int i = 0; i < SEGL; ++i) {
        int t = t0 + i;
        size_t idx = (size_t)t * 256 + ((c + t) & 255);
        float v = base[idx];
        s = fmaxf(s + v, 0.f);
        base[idx] = s;
    }
    if (seg == SEGS - 1) last[batch * 256 + ((c + 255) & 255)] = s;
}

// ---------- launch ----------
extern "C" void kernel_launch(void* const* d_in, const int* in_sizes, int n_in,
                              void* d_out, int out_size, void* d_ws, size_t ws_size,
                              hipStream_t stream) {
    const float* x      = (const float*)d_in[0];
    const float* hidden = (const float*)d_in[1];
    const float* W0 = (const float*)d_in[2];
    const float* b0 = (const float*)d_in[3];
    const float* W1 = (const float*)d_in[4];
    const float* b1 = (const float*)d_in[5];
    const float* W2 = (const float*)d_in[6];
    const float* b2 = (const float*)d_in[7];
    const float* W3 = (const float*)d_in[8];
    const float* b3 = (const float*)d_in[9];

    float* out  = (float*)d_out;
    float* last = out + (size_t)M * D;

    char* ws = (char*)d_ws;
    __bf16* wpb    = (__bf16*)ws;                 // 524,288 B (Wp0, Wp1)
    float2* seg_am = (float2*)(ws + 524288);      // 2,097,152 B

    cvt_w<<<128, 256, 0, stream>>>(W0, W1, W2, W3, wpb);
    gln_fused<<<M / 64, 512, 0, stream>>>(x, wpb, b0, b1, b2, b3, out, seg_am);
    scan_apply<<<(B * D * SEGS) / 256, 256, 0, stream>>>(out, seg_am, hidden, last);
}

// Round 14
// 84.150 us; speedup vs baseline: 1.1354x; 1.0150x over previous
//
#include <hip/hip_runtime.h>
#include <hip/hip_bf16.h>
#include <cstdint>
#include <cstddef>

// ---------- types ----------
typedef __bf16 bf16x8 __attribute__((ext_vector_type(8)));
typedef float  f32x4  __attribute__((ext_vector_type(4)));

static constexpr int B  = 16;
static constexpr int T  = 4096;
static constexpr int D  = 256;
static constexpr int M  = B * T;          // 65536 rows
static constexpr int SEGS = 64;           // segments along T
static constexpr int SEGL = T / SEGS;     // 64 steps per segment

// raw barrier (no vmcnt(0) drain) + compiler fences; LGKM0 fences LDS
// producer->consumer edges. Global prefetches/stores stay in flight across
// barriers; consumers are guarded by compiler-inserted vmcnt data-dep waits.
#define RBAR() do { asm volatile("" ::: "memory"); \
                    __builtin_amdgcn_s_barrier();  \
                    asm volatile("" ::: "memory"); } while (0)
#define LGKM0() asm volatile("s_waitcnt lgkmcnt(0)" ::: "memory")

// fast sigmoid: v_exp_f32 + v_rcp_f32 instead of IEEE div (~10 instrs).
// NOTE (r13): the exp2f(fmaf(...)) variant with pre-scaled bias REGRESSED
// ~5us despite fewer ops — keep __expf form; measurement wins.
__device__ __forceinline__ float sigmoid_fast(float v) {
    return __builtin_amdgcn_rcpf(1.0f + __expf(-v));
}

// ---------- build fragment-major interleaved bf16 weights ----------
// Wp_s element layout: [(ks*32 + fg)*64 + lane] * 8 bf16 elems, where
//   fg = vcol>>4 (0..31), lane = kg*16 + rl, elem ko in [0,8)
//   stored value = W_{s,gate}[rc][ks*32 + kg*8 + ko]
// vcol decomposition: w = fg>>2 (col-wave 0..7), f = fg&3, q = f>>1,
//   gate = f&1, rc = w*32 + 2*rl + q  (lane rl holds 2 ADJACENT real cols)
__global__ void cvt_w(const float* __restrict__ W0, const float* __restrict__ W1,
                      const float* __restrict__ W2, const float* __restrict__ W3,
                      __bf16* __restrict__ wp) {
    int i = blockIdx.x * blockDim.x + threadIdx.x;   // 0..32767
    int s    = i >> 14;
    int r    = i & 16383;
    int ks   = r >> 11;          // 0..7
    int fg   = (r >> 6) & 31;    // 0..31
    int lane = r & 63;
    int kg = lane >> 4, rl = lane & 15;
    int w = fg >> 2, f = fg & 3;
    int q = f >> 1, gate = f & 1;
    int rc = w * 32 + 2 * rl + q;
    const float* src = (s == 0) ? (gate ? W1 : W0) : (gate ? W3 : W2);
    const float* p = src + (size_t)rc * 256 + ks * 32 + kg * 8;
    bf16x8 o;
#pragma unroll
    for (int j = 0; j < 8; ++j) o[j] = (__bf16)p[j];
    *reinterpret_cast<bf16x8*>(wp + (size_t)s * 131072 +
                               ((size_t)((ks * 32 + fg) * 64 + lane)) * 8) = o;
}

// ---------- fused two-stage gated-linear + per-segment scan compose ----------
// Session-converged configuration (= r10, verified 84.0 us total):
// single 64-row tile, 512 thr / 8 waves, 32 KiB LDS, raw barriers,
// top-of-loop 2-deep B prefetch from L2, 2 blocks/CU.
// Falsified this session: occupancy-bound (r5), A-read bank conflicts (r6),
// barrier vmcnt-drain (r10), LDS weight streaming (r11), deeper B-prefetch
// (r12), exp2-folded sigmoid (r13). Confirmed wins baked in: two-stage
// fusion via in-place LDS tile, scan_seg fusion (row-split ftile), scan_bound
// fold into scan_apply, v_rcp sigmoid, store-drain overlap.
__launch_bounds__(512, 4)
__global__ void gln_fused(const float* __restrict__ x,
                          const __bf16* __restrict__ wp,
                          const float* __restrict__ b0, const float* __restrict__ b1,
                          const float* __restrict__ b2, const float* __restrict__ b3,
                          float* __restrict__ out,
                          float2* __restrict__ seg_am) {
    __shared__ char tile[32768];           // [64][256] bf16, chunk-XOR swizzle

    const int tid  = threadIdx.x;          // 0..511
    const int lane = tid & 63;
    const int wid  = tid >> 6;             // 0..7
    const int rl   = lane & 15;
    const int kg   = lane >> 4;            // 0..3
    const int row0 = blockIdx.x * 64;

    const __bf16* wv0 = wp + ((size_t)(wid * 4) * 64 + lane) * 8;
    const __bf16* wv1 = wv0 + 131072;

    bf16x8 bbuf[2][4];
    auto loadB = [&](int p, const __bf16* wvb, int ks) {
#pragma unroll
        for (int f = 0; f < 4; ++f)
            bbuf[p][f] = *reinterpret_cast<const bf16x8*>(wvb + ks * 16384 + f * 512);
    };

    // ---- stage x rows [row0, row0+64) into LDS as bf16 ----
    {
        int r  = tid >> 3;         // 0..63
        int c0 = tid & 7;          // base 16B-chunk
        const float* xr = x + (size_t)(row0 + r) * 256;
        float4 xa[4][2];
#pragma unroll
        for (int ci = 0; ci < 4; ++ci) {
            const float4* p = reinterpret_cast<const float4*>(xr + (c0 + ci * 8) * 8);
            xa[ci][0] = p[0];
            xa[ci][1] = p[1];
        }
#pragma unroll
        for (int ci = 0; ci < 4; ++ci) {
            int ck = c0 + ci * 8;  // logical chunk 0..31
            int pc = ck ^ ((r & 7) << 2);
            bf16x8 o = { (__bf16)xa[ci][0].x, (__bf16)xa[ci][0].y,
                         (__bf16)xa[ci][0].z, (__bf16)xa[ci][0].w,
                         (__bf16)xa[ci][1].x, (__bf16)xa[ci][1].y,
                         (__bf16)xa[ci][1].z, (__bf16)xa[ci][1].w };
            *reinterpret_cast<bf16x8*>(&tile[r * 512 + pc * 16]) = o;
        }
    }
    loadB(0, wv0, 0);              // stays in flight across raw barrier
    LGKM0(); RBAR();

    f32x4 acc[4][4];

    // one GEMM stage: A from LDS (64 rows, K=256), B 2-deep pipelined from L2.
    auto run_stage = [&](const __bf16* wvb) {
#pragma unroll
        for (int m = 0; m < 4; ++m)
#pragma unroll
            for (int f = 0; f < 4; ++f) acc[m][f] = (f32x4){0.f, 0.f, 0.f, 0.f};
#pragma unroll
        for (int ks = 0; ks < 8; ++ks) {
            if (ks < 7) loadB((ks + 1) & 1, wvb, ks + 1);   // prefetch next ks
            bf16x8 aR[4];
#pragma unroll
            for (int m = 0; m < 4; ++m) {
                int row = m * 16 + rl;
                int pc  = (ks * 4 + kg) ^ ((row & 7) << 2);
                aR[m] = *reinterpret_cast<const bf16x8*>(&tile[row * 512 + pc * 16]);
            }
#pragma unroll
            for (int m = 0; m < 4; ++m)
#pragma unroll
                for (int f = 0; f < 4; ++f)
                    acc[m][f] = __builtin_amdgcn_mfma_f32_16x16x32_bf16(
                        aR[m], bbuf[ks & 1][f], acc[m][f], 0, 0, 0);
        }
    };

    const int rc0 = wid * 32 + 2 * rl;     // even real col of this lane

    // ---- stage 0: h = (x@W0^T+b0) * sigmoid(x@W1^T+b1) ----
    run_stage(wv0);
    loadB(0, wv1, 0);              // stage-1 ks0 prefetch (survives barriers)
    RBAR();                        // x reads consumed (data-dep); overwrite ok
    {
        float2 bb0 = *reinterpret_cast<const float2*>(b0 + rc0);
        float2 bb1 = *reinterpret_cast<const float2*>(b1 + rc0);
        int cb  = rc0 * 2;                 // byte col (4-aligned)
        int ck  = cb >> 4;                 // logical chunk
        int off = cb & 15;
#pragma unroll
        for (int m = 0; m < 4; ++m)
#pragma unroll
            for (int j = 0; j < 4; ++j) {
                int row = m * 16 + kg * 4 + j;
                float he = (acc[m][0][j] + bb0.x) * sigmoid_fast(acc[m][1][j] + bb1.x);
                float ho = (acc[m][2][j] + bb0.y) * sigmoid_fast(acc[m][3][j] + bb1.y);
                unsigned short ue = __builtin_bit_cast(unsigned short, (__bf16)he);
                unsigned short uo = __builtin_bit_cast(unsigned short, (__bf16)ho);
                unsigned int u = ((unsigned int)uo << 16) | (unsigned int)ue;
                int pc = ck ^ ((row & 7) << 2);
                *reinterpret_cast<unsigned int*>(&tile[row * 512 + pc * 16 + off]) = u;
            }
    }
    LGKM0(); RBAR();

    // ---- stage 1: out = (h@W2^T+b2) * sigmoid(h@W3^T+b3) ----
    run_stage(wv1);

    // epilogue: gated values -> regs only
    float2 ov[16];
    {
        float2 bb2 = *reinterpret_cast<const float2*>(b2 + rc0);
        float2 bb3 = *reinterpret_cast<const float2*>(b3 + rc0);
#pragma unroll
        for (int m = 0; m < 4; ++m)
#pragma unroll
            for (int j = 0; j < 4; ++j) {
                float he = (acc[m][0][j] + bb2.x) * sigmoid_fast(acc[m][1][j] + bb3.x);
                float ho = (acc[m][2][j] + bb2.y) * sigmoid_fast(acc[m][3][j] + bb3.y);
                float2 o; o.x = he; o.y = ho;
                ov[m * 4 + j] = o;
            }
    }
    RBAR();                        // h reads consumed; tile reusable

    // ---- row-split ftile + fused scan_seg compose (state in regs) ----
    float* ftile = reinterpret_cast<float*>(tile);   // [32][256] f32 = 32 KiB
#pragma unroll
    for (int m = 0; m < 2; ++m)
#pragma unroll
        for (int j = 0; j < 4; ++j) {
            int row = m * 16 + kg * 4 + j;
            int col = rc0 ^ ((row & 7) << 2);
            *reinterpret_cast<float2*>(&ftile[row * 256 + col]) = ov[m * 4 + j];
        }
    LGKM0(); RBAR();

    const int batch = row0 >> 12;          // row0 / T
    const int t0    = row0 & 4095;
    const int seg   = t0 >> 6;
    float A = 0.f, Mx = -1e30f;
    int cc = 0;
    if (tid < 256) {
        cc = (tid + t0) & 255;
#pragma unroll 8
        for (int i = 0; i < 32; ++i) {
            int col = ((cc + i) & 255) ^ ((i & 7) << 2);
            float v = ftile[i * 256 + col];
            A += v;
            Mx = fmaxf(Mx + v, 0.f);
        }
    }
    RBAR();                        // part-1 reads consumed before overwrite
#pragma unroll
    for (int m = 2; m < 4; ++m)
#pragma unroll
        for (int j = 0; j < 4; ++j) {
            int row = m * 16 + kg * 4 + j;
            int pr  = row & 31;
            int col = rc0 ^ ((pr & 7) << 2);
            *reinterpret_cast<float2*>(&ftile[pr * 256 + col]) = ov[m * 4 + j];
        }

    // global stores: not drained by the raw barrier below; overlap compose
#pragma unroll
    for (int m = 0; m < 4; ++m)
#pragma unroll
        for (int j = 0; j < 4; ++j) {
            int row = m * 16 + kg * 4 + j;
            *reinterpret_cast<float2*>(out + (size_t)(row0 + row) * 256 + rc0) =
                ov[m * 4 + j];
        }
    LGKM0(); RBAR();

    if (tid < 256) {
#pragma unroll 8
        for (int i = 32; i < 64; ++i) {
            int pr  = i - 32;
            int col = ((cc + i) & 255) ^ ((pr & 7) << 2);
            float v = ftile[pr * 256 + col];
            A += v;
            Mx = fmaxf(Mx + v, 0.f);
        }
        float2 o; o.x = A; o.y = Mx;
        seg_am[(size_t)(batch * SEGS + seg) * 256 + tid] = o;
    }
    // stores drain at wave retirement
}

// ---------- scan apply with integrated boundary lookback ----------
// Block = one (batch, seg) x 256 cols. Redundantly composes seg_am[0..seg)
// (<=63 serial fmax steps, L2/L3-resident).
__global__ void scan_apply(float* __restrict__ bio,
                           const float2* __restrict__ seg_am,
                           const float* __restrict__ hidden,
                           float* __restrict__ last) {
    int tid   = blockIdx.x * blockDim.x + threadIdx.x;
    int c     = tid & 255;
    int rest  = tid >> 8;
    int batch = rest & 15;
    int seg   = rest >> 4;
    float s = hidden[batch * 256 + ((c + 255) & 255)];
    const float2* am = seg_am + ((size_t)batch * SEGS) * 256 + c;
    for (int k = 0; k < seg; ++k) {
        float2 a = am[(size_t)k * 256];
        s = fmaxf(s + a.x, a.y);
    }
    float* base = bio + (size_t)batch * T * D;
    int t0 = seg * SEGL;
#pragma unroll 8
    for (int i = 0; i < SEGL; ++i) {
        int t = t0 + i;
        size_t idx = (size_t)t * 256 + ((c + t) & 255);
        float v = base[idx];
        s = fmaxf(s + v, 0.f);
        base[idx] = s;
    }
    if (seg == SEGS - 1) last[batch * 256 + ((c + 255) & 255)] = s;
}

// ---------- launch ----------
extern "C" void kernel_launch(void* const* d_in, const int* in_sizes, int n_in,
                              void* d_out, int out_size, void* d_ws, size_t ws_size,
                              hipStream_t stream) {
    const float* x      = (const float*)d_in[0];
    const float* hidden = (const float*)d_in[1];
    const float* W0 = (const float*)d_in[2];
    const float* b0 = (const float*)d_in[3];
    const float* W1 = (const float*)d_in[4];
    const float* b1 = (const float*)d_in[5];
    const float* W2 = (const float*)d_in[6];
    const float* b2 = (const float*)d_in[7];
    const float* W3 = (const float*)d_in[8];
    const float* b3 = (const float*)d_in[9];

    float* out  = (float*)d_out;
    float* last = out + (size_t)M * D;

    char* ws = (char*)d_ws;
    __bf16* wpb    = (__bf16*)ws;                 // 524,288 B (Wp0, Wp1)
    float2* seg_am = (float2*)(ws + 524288);      // 2,097,152 B

    cvt_w<<<128, 256, 0, stream>>>(W0, W1, W2, W3, wpb);
    gln_fused<<<M / 64, 512, 0, stream>>>(x, wpb, b0, b1, b2, b3, out, seg_am);
    scan_apply<<<(B * D * SEGS) / 256, 256, 0, stream>>>(out, seg_am, hidden, last);
}